// Round 4
// baseline (1127.385 us; speedup 1.0000x reference)
//
#include <hip/hip_runtime.h>

#define N_VOX 262144
#define C 64
#define K_VOL 27
#define P 65536
#define NPAIR (K_VOL * P)

// ---- binning geometry ----
#define BIN_ROWS 256
#define NBINS (N_VOX / BIN_ROWS)       // 1024
#define CAP 2048                       // records accepted per bin (mean 1728, 7.7 sigma headroom)
#define REC_SLOTS 2464                 // CAP + 27*15 k-padding headroom
#define MAXG (REC_SLOTS / 16)          // 154 groups max

// ---- ws layout (bytes) ----
#define W_SZ      (K_VOL * 2 * 4 * 64 * 16)        // 221184 per half
#define W_HI_OFF  0
#define W_LO_OFF  W_SZ
#define CNT_OFF   (2 * W_SZ)                       // 442368
#define OCNT_OFF  (CNT_OFF + NBINS * 4)
#define OVF_CAP   4096
#define OVF_OFF   (OCNT_OFF + 64)
#define REC_OFF   (OVF_OFF + OVF_CAP * 8)          // 479296
#define WS_NEED   ((size_t)REC_OFF + (size_t)NBINS * CAP * 4)   // ~8.87 MB

typedef __attribute__((ext_vector_type(8))) short bf16x8;
typedef __attribute__((ext_vector_type(4))) float f32x4;

__device__ inline unsigned short cvt_bf16_rne(float x) {
    unsigned u = __builtin_bit_cast(unsigned, x);
    u += 0x7fff + ((u >> 16) & 1);
    return (unsigned short)(u >> 16);
}
__device__ inline float bf16f(unsigned short h) {
    unsigned u = (unsigned)h << 16;
    return __builtin_bit_cast(float, u);
}

// ---------- phase 0: W -> bf16 hi/lo MFMA fragments in ws ----------
__global__ void w_prep(const float* __restrict__ kern, unsigned char* __restrict__ ws) {
    const int k = blockIdx.x, lane = threadIdx.x;     // 64 threads
    const int g4 = lane >> 4, col = lane & 15;
    const float* Wk = kern + (size_t)k * C * C;
    bf16x8* hi = (bf16x8*)(ws + W_HI_OFF);
    bf16x8* lo = (bf16x8*)(ws + W_LO_OFF);
    #pragma unroll
    for (int kt = 0; kt < 2; ++kt)
        #pragma unroll
        for (int nt = 0; nt < 4; ++nt) {
            bf16x8 h, l;
            #pragma unroll
            for (int i = 0; i < 8; ++i) {
                float w = Wk[(size_t)(kt * 32 + g4 * 8 + i) * C + nt * 16 + col];
                unsigned short hs = cvt_bf16_rne(w);
                h[i] = (short)hs;
                l[i] = (short)cvt_bf16_rne(w - bf16f(hs));
            }
            int idx = ((k * 2 + kt) * 4 + nt) * 64 + lane;
            hi[idx] = h;
            lo[idx] = l;
        }
}

// ---------- phase 1: scatter pairs into per-bin record lists ----------
__global__ void binning(const int* __restrict__ src, const int* __restrict__ tgt,
                        unsigned char* __restrict__ ws) {
    unsigned* cnt  = (unsigned*)(ws + CNT_OFF);
    unsigned* ocnt = (unsigned*)(ws + OCNT_OFF);
    uint2*    ovf  = (uint2*)(ws + OVF_OFF);
    unsigned* rec  = (unsigned*)(ws + REC_OFF);
    for (int j = blockIdx.x * blockDim.x + threadIdx.x; j < NPAIR;
         j += gridDim.x * blockDim.x) {
        int k = j >> 16;                      // P == 65536
        unsigned s = (unsigned)src[j];
        unsigned t = (unsigned)tgt[j];
        unsigned r = ((t & 255u) << 23) | ((unsigned)k << 18) | s;
        unsigned bin = t >> 8;
        unsigned pos = atomicAdd(&cnt[bin], 1u);
        if (pos < CAP) rec[(size_t)bin * CAP + pos] = r;
        else {
            unsigned op = atomicAdd(ocnt, 1u);
            if (op < OVF_CAP) ovf[op] = make_uint2(((unsigned)k << 18) | s, t);
        }
    }
}

// ---------- phase 2: per-bin k-sorted MFMA + LDS accumulation ----------
__global__ __launch_bounds__(512, 4) void conv_bin(
    const float* __restrict__ feat,
    const unsigned char* __restrict__ ws,
    float* __restrict__ out)
{
    __shared__ float tile[(BIN_ROWS + 1) * C];      // 65792 B, row 256 = garbage row
    __shared__ unsigned srec[REC_SLOTS];            // 9856 B, k-sorted padded records
    __shared__ unsigned khist[K_VOL], koff[K_VOL];
    __shared__ unsigned short grp2k[MAXG + 2];
    __shared__ unsigned sG;

    const int bin  = blockIdx.x;
    const int tid  = threadIdx.x;
    const int wave = tid >> 6, lane = tid & 63;
    const int g4 = lane >> 4, col = lane & 15;

    const unsigned* cnt = (const unsigned*)(ws + CNT_OFF);
    const unsigned* rec = (const unsigned*)(ws + REC_OFF) + (size_t)bin * CAP;
    const unsigned nrec = min(cnt[bin], (unsigned)CAP);

    // init: zero tile, dummy-fill sorted records, zero k-hist
    for (int i = tid; i < (BIN_ROWS + 1) * C; i += 512) tile[i] = 0.f;
    for (int i = tid; i < REC_SLOTS; i += 512) srec[i] = 0xFFFFFFFFu;
    if (tid < K_VOL) khist[tid] = 0u;
    __syncthreads();

    // pass 1: k histogram (coalesced global reads)
    for (unsigned i = tid; i < nrec; i += 512)
        atomicAdd(&khist[(rec[i] >> 18) & 31u], 1u);
    __syncthreads();

    // scan: padded segment bases + group->k map (27/154 elems: serial thread 0)
    if (tid == 0) {
        unsigned base = 0, g = 0;
        for (int k = 0; k < K_VOL; ++k) {
            koff[k] = base;
            unsigned ng = (khist[k] + 15u) >> 4;
            for (unsigned q = 0; q < ng; ++q) grp2k[g++] = (unsigned short)k;
            base += ng << 4;
        }
        sG = g;
    }
    __syncthreads();
    const unsigned G = sG;

    // pass 2: scatter records into k-sorted padded LDS slots
    for (unsigned i = tid; i < nrec; i += 512) {
        unsigned r = rec[i];
        unsigned pos = atomicAdd(&koff[(r >> 18) & 31u], 1u);
        srec[pos] = r;
    }
    __syncthreads();

    // compute: waves take contiguous group ranges (few k-changes per wave)
    const bf16x8* whi = (const bf16x8*)(ws + W_HI_OFF);
    const bf16x8* wlo = (const bf16x8*)(ws + W_LO_OFF);
    const unsigned gs = (G * (unsigned)wave) >> 3;
    const unsigned ge = (G * (unsigned)(wave + 1)) >> 3;

    bf16x8 Bhi[2][4], Blo[2][4];
    int curk = -1;

    for (unsigned g = gs; g < ge; ++g) {
        const int k = (int)grp2k[g];
        if (k != curk) {
            curk = k;
            #pragma unroll
            for (int kt = 0; kt < 2; ++kt)
                #pragma unroll
                for (int nt = 0; nt < 4; ++nt) {
                    int idx = ((k * 2 + kt) * 4 + nt) * 64 + lane;
                    Bhi[kt][nt] = whi[idx];
                    Blo[kt][nt] = wlo[idx];
                }
        }

        // this lane's A-row record + the 4 records whose D-rows it owns
        const unsigned rb = g * 16;
        const unsigned myrec = srec[rb + col];
        const unsigned q0 = srec[rb + g4 * 4 + 0];
        const unsigned q1 = srec[rb + g4 * 4 + 1];
        const unsigned q2 = srec[rb + g4 * 4 + 2];
        const unsigned q3 = srec[rb + g4 * 4 + 3];
        const int row0 = (q0 == 0xFFFFFFFFu) ? 256 : (int)((q0 >> 23) & 255u);
        const int row1 = (q1 == 0xFFFFFFFFu) ? 256 : (int)((q1 >> 23) & 255u);
        const int row2 = (q2 == 0xFFFFFFFFu) ? 256 : (int)((q2 >> 23) & 255u);
        const int row3 = (q3 == 0xFFFFFFFFu) ? 256 : (int)((q3 >> 23) & 255u);

        // gather this lane's feat chunk (dummy records read feat[0x3FFFF]: harmless)
        const float* fr = feat + (size_t)(myrec & 0x3FFFFu) * C + g4 * 8;
        f32x4 ra0 = *(const f32x4*)(fr);
        f32x4 ra1 = *(const f32x4*)(fr + 4);
        f32x4 ra2 = *(const f32x4*)(fr + 32);
        f32x4 ra3 = *(const f32x4*)(fr + 36);

        // convert to bf16 hi/lo A-frags
        bf16x8 Ahi[2], Alo[2];
        #pragma unroll
        for (int i = 0; i < 4; ++i) {
            float x0 = ra0[i], x1 = ra1[i], x2 = ra2[i], x3 = ra3[i];
            unsigned short h;
            h = cvt_bf16_rne(x0); Ahi[0][i]     = (short)h; Alo[0][i]     = (short)cvt_bf16_rne(x0 - bf16f(h));
            h = cvt_bf16_rne(x1); Ahi[0][4 + i] = (short)h; Alo[0][4 + i] = (short)cvt_bf16_rne(x1 - bf16f(h));
            h = cvt_bf16_rne(x2); Ahi[1][i]     = (short)h; Alo[1][i]     = (short)cvt_bf16_rne(x2 - bf16f(h));
            h = cvt_bf16_rne(x3); Ahi[1][4 + i] = (short)h; Alo[1][4 + i] = (short)cvt_bf16_rne(x3 - bf16f(h));
        }

        // 24 MFMAs: 4 n-tiles x 2 k-tiles x {hi*hi, lo*hi, hi*lo}
        f32x4 acc[4] = {f32x4{0.f,0.f,0.f,0.f}, f32x4{0.f,0.f,0.f,0.f},
                        f32x4{0.f,0.f,0.f,0.f}, f32x4{0.f,0.f,0.f,0.f}};
        #pragma unroll
        for (int kt = 0; kt < 2; ++kt) {
            #pragma unroll
            for (int nt = 0; nt < 4; ++nt)
                acc[nt] = __builtin_amdgcn_mfma_f32_16x16x32_bf16(Ahi[kt], Bhi[kt][nt], acc[nt], 0, 0, 0);
            #pragma unroll
            for (int nt = 0; nt < 4; ++nt)
                acc[nt] = __builtin_amdgcn_mfma_f32_16x16x32_bf16(Alo[kt], Bhi[kt][nt], acc[nt], 0, 0, 0);
            #pragma unroll
            for (int nt = 0; nt < 4; ++nt)
                acc[nt] = __builtin_amdgcn_mfma_f32_16x16x32_bf16(Ahi[kt], Blo[kt][nt], acc[nt], 0, 0, 0);
        }

        // accumulate into LDS out-tile (atomic: duplicate tgts + cross-wave)
        float* t0 = &tile[row0 * C + col];
        float* t1 = &tile[row1 * C + col];
        float* t2 = &tile[row2 * C + col];
        float* t3 = &tile[row3 * C + col];
        #pragma unroll
        for (int nt = 0; nt < 4; ++nt) {
            atomicAdd(t0 + nt * 16, acc[nt][0]);
            atomicAdd(t1 + nt * 16, acc[nt][1]);
            atomicAdd(t2 + nt * 16, acc[nt][2]);
            atomicAdd(t3 + nt * 16, acc[nt][3]);
        }
    }
    __syncthreads();

    // stream the tile out: each output element written exactly once, coalesced
    float* ob = out + (size_t)bin * BIN_ROWS * C;
    for (int i = tid * 4; i < BIN_ROWS * C; i += 512 * 4)
        *(float4*)(ob + i) = *(const float4*)&tile[i];
}

// ---------- phase 3: exact-fp32 fixup for overflow records (normally none) ----------
__global__ void ovf_fix(const float* __restrict__ feat, const float* __restrict__ kern,
                        const unsigned char* __restrict__ ws, float* __restrict__ out) {
    const unsigned* ocnt = (const unsigned*)(ws + OCNT_OFF);
    const uint2*    ovf  = (const uint2*)(ws + OVF_OFF);
    const unsigned n = min(*ocnt, (unsigned)OVF_CAP);
    const int ch = threadIdx.x & 63;
    const unsigned r0 = (blockIdx.x * blockDim.x + threadIdx.x) >> 6;
    const unsigned stride = (gridDim.x * blockDim.x) >> 6;
    for (unsigned r = r0; r < n; r += stride) {
        uint2 e = ovf[r];
        unsigned s = e.x & 0x3FFFFu, k = (e.x >> 18) & 31u, t = e.y;
        const float* fr = feat + (size_t)s * C;
        const float* Wk = kern + (size_t)k * C * C + ch;
        float a = 0.f;
        for (int i = 0; i < C; ++i) a = fmaf(fr[i], Wk[(size_t)i * C], a);
        unsafeAtomicAdd(out + (size_t)t * C + ch, a);
    }
}

// ---------- fallback (round-3 kernel) if ws is too small ----------
#define FB_PAIRS_PER_WAVE 256
#define FB_NBATCH 16
__global__ __launch_bounds__(256) void conv_mfma(
    const float* __restrict__ feat, const float* __restrict__ kern,
    const int* __restrict__ src_ids, const int* __restrict__ tgt_ids,
    float* __restrict__ out)
{
    const int k = blockIdx.y, wave = threadIdx.x >> 6, lane = threadIdx.x & 63;
    const int g = lane >> 4, col = lane & 15;
    bf16x8 Bhi[2][4], Blo[2][4];
    {
        const float* Wk = kern + (size_t)k * C * C;
        #pragma unroll
        for (int kt = 0; kt < 2; ++kt)
            #pragma unroll
            for (int nt = 0; nt < 4; ++nt)
                #pragma unroll
                for (int i = 0; i < 8; ++i) {
                    float w = Wk[(size_t)(kt * 32 + g * 8 + i) * C + nt * 16 + col];
                    unsigned short h = cvt_bf16_rne(w);
                    Bhi[kt][nt][i] = (short)h;
                    Blo[kt][nt][i] = (short)cvt_bf16_rne(w - bf16f(h));
                }
    }
    const int pb0 = (blockIdx.x * 4 + wave) * FB_PAIRS_PER_WAVE;
    const int* srcp = src_ids + (size_t)k * P + pb0;
    const int* tgtp = tgt_ids + (size_t)k * P + pb0;
    for (int b = 0; b < FB_NBATCH; ++b) {
        int sv = srcp[b * 16 + col];
        const float* fr = feat + (size_t)sv * C + g * 8;
        f32x4 ra0 = *(const f32x4*)(fr), ra1 = *(const f32x4*)(fr + 4);
        f32x4 ra2 = *(const f32x4*)(fr + 32), ra3 = *(const f32x4*)(fr + 36);
        int tg0 = tgtp[b * 16 + g * 4 + 0], tg1 = tgtp[b * 16 + g * 4 + 1];
        int tg2 = tgtp[b * 16 + g * 4 + 2], tg3 = tgtp[b * 16 + g * 4 + 3];
        bf16x8 Ahi[2], Alo[2];
        #pragma unroll
        for (int i = 0; i < 4; ++i) {
            float x0 = ra0[i], x1 = ra1[i], x2 = ra2[i], x3 = ra3[i];
            unsigned short h;
            h = cvt_bf16_rne(x0); Ahi[0][i]     = (short)h; Alo[0][i]     = (short)cvt_bf16_rne(x0 - bf16f(h));
            h = cvt_bf16_rne(x1); Ahi[0][4 + i] = (short)h; Alo[0][4 + i] = (short)cvt_bf16_rne(x1 - bf16f(h));
            h = cvt_bf16_rne(x2); Ahi[1][i]     = (short)h; Alo[1][i]     = (short)cvt_bf16_rne(x2 - bf16f(h));
            h = cvt_bf16_rne(x3); Ahi[1][4 + i] = (short)h; Alo[1][4 + i] = (short)cvt_bf16_rne(x3 - bf16f(h));
        }
        f32x4 acc[4] = {f32x4{0.f,0.f,0.f,0.f}, f32x4{0.f,0.f,0.f,0.f},
                        f32x4{0.f,0.f,0.f,0.f}, f32x4{0.f,0.f,0.f,0.f}};
        #pragma unroll
        for (int kt = 0; kt < 2; ++kt) {
            #pragma unroll
            for (int nt = 0; nt < 4; ++nt)
                acc[nt] = __builtin_amdgcn_mfma_f32_16x16x32_bf16(Ahi[kt], Bhi[kt][nt], acc[nt], 0, 0, 0);
            #pragma unroll
            for (int nt = 0; nt < 4; ++nt)
                acc[nt] = __builtin_amdgcn_mfma_f32_16x16x32_bf16(Alo[kt], Bhi[kt][nt], acc[nt], 0, 0, 0);
            #pragma unroll
            for (int nt = 0; nt < 4; ++nt)
                acc[nt] = __builtin_amdgcn_mfma_f32_16x16x32_bf16(Ahi[kt], Blo[kt][nt], acc[nt], 0, 0, 0);
        }
        float* o0 = out + (size_t)tg0 * C + col;
        float* o1 = out + (size_t)tg1 * C + col;
        float* o2 = out + (size_t)tg2 * C + col;
        float* o3 = out + (size_t)tg3 * C + col;
        #pragma unroll
        for (int nt = 0; nt < 4; ++nt) {
            unsafeAtomicAdd(o0 + nt * 16, acc[nt][0]);
            unsafeAtomicAdd(o1 + nt * 16, acc[nt][1]);
            unsafeAtomicAdd(o2 + nt * 16, acc[nt][2]);
            unsafeAtomicAdd(o3 + nt * 16, acc[nt][3]);
        }
    }
}

extern "C" void kernel_launch(void* const* d_in, const int* in_sizes, int n_in,
                              void* d_out, int out_size, void* d_ws, size_t ws_size,
                              hipStream_t stream)
{
    const float* feat = (const float*)d_in[0];
    const float* kern = (const float*)d_in[1];
    const int*   src  = (const int*)d_in[2];
    const int*   tgt  = (const int*)d_in[3];
    float* out = (float*)d_out;
    unsigned char* ws = (unsigned char*)d_ws;

    if (ws_size >= WS_NEED) {
        // zero bin counters + overflow counter (ws is poisoned 0xAA each call)
        hipMemsetAsync(ws + CNT_OFF, 0, NBINS * 4 + 64, stream);
        w_prep<<<K_VOL, 64, 0, stream>>>(kern, ws);
        binning<<<2048, 256, 0, stream>>>(src, tgt, ws);
        conv_bin<<<NBINS, 512, 0, stream>>>(feat, ws, out);
        ovf_fix<<<16, 256, 0, stream>>>(feat, kern, ws, out);
    } else {
        // fallback: atomic-scatter kernel
        hipMemsetAsync(out, 0, (size_t)N_VOX * C * sizeof(float), stream);
        dim3 grid(P / (FB_PAIRS_PER_WAVE * 4), K_VOL);
        conv_mfma<<<grid, 256, 0, stream>>>(feat, kern, src, tgt, out);
    }
}

// Round 7
// 832.850 us; speedup vs baseline: 1.3536x; 1.3536x over previous
//
#include <hip/hip_runtime.h>

#define N_VOX 262144
#define C 64
#define K_VOL 27
#define P 65536
#define NPAIR (K_VOL * P)

// ---- binning geometry ----
#define BIN_ROWS 256
#define NBINS (N_VOX / BIN_ROWS)       // 1024
#define CAP 2048                       // mean 1728, +7.7 sigma headroom
#define REC_SLOTS 2464                 // CAP + 27*15 k-padding headroom
#define MAXG (REC_SLOTS / 16)          // 154

// ---- ws layout (bytes) ----
#define W_SZ      (K_VOL * 2 * 4 * 64 * 16)        // 221184 per half
#define W_HI_OFF  0
#define W_LO_OFF  W_SZ
#define CNT_OFF   (2 * W_SZ)
#define OCNT_OFF  (CNT_OFF + NBINS * 4)
#define OVF_CAP   4096
#define OVF_OFF   (OCNT_OFF + 64)
#define REC_OFF   (OVF_OFF + OVF_CAP * 8)
#define WS_NEED   ((size_t)REC_OFF + (size_t)NBINS * CAP * 4)   // ~8.87 MB

typedef __attribute__((ext_vector_type(8))) short bf16x8;
typedef __attribute__((ext_vector_type(4))) float f32x4;

__device__ inline unsigned short cvt_bf16_rne(float x) {
    unsigned u = __builtin_bit_cast(unsigned, x);
    u += 0x7fff + ((u >> 16) & 1);
    return (unsigned short)(u >> 16);
}
__device__ inline float bf16f(unsigned short h) {
    unsigned u = (unsigned)h << 16;
    return __builtin_bit_cast(float, u);
}

// ---------- phase 0: W -> bf16 hi/lo MFMA fragments in ws ----------
__global__ void w_prep(const float* __restrict__ kern, unsigned char* __restrict__ ws) {
    const int k = blockIdx.x, lane = threadIdx.x;     // 64 threads
    const int g4 = lane >> 4, col = lane & 15;
    const float* Wk = kern + (size_t)k * C * C;
    bf16x8* hi = (bf16x8*)(ws + W_HI_OFF);
    bf16x8* lo = (bf16x8*)(ws + W_LO_OFF);
    #pragma unroll
    for (int kt = 0; kt < 2; ++kt)
        #pragma unroll
        for (int nt = 0; nt < 4; ++nt) {
            bf16x8 h, l;
            #pragma unroll
            for (int i = 0; i < 8; ++i) {
                float w = Wk[(size_t)(kt * 32 + g4 * 8 + i) * C + nt * 16 + col];
                unsigned short hs = cvt_bf16_rne(w);
                h[i] = (short)hs;
                l[i] = (short)cvt_bf16_rne(w - bf16f(hs));
            }
            int idx = ((k * 2 + kt) * 4 + nt) * 64 + lane;
            hi[idx] = h;
            lo[idx] = l;
        }
}

// ---------- phase 1: two-level binning (LDS histogram + range reservation) ----------
#define BIN_BLOCKS 256
#define BIN_THREADS 512
#define CHUNK (NPAIR / BIN_BLOCKS)     // 6912, exact

__global__ __launch_bounds__(BIN_THREADS) void binning(
    const int* __restrict__ src, const int* __restrict__ tgt,
    unsigned char* __restrict__ ws)
{
    __shared__ unsigned lcnt[NBINS];    // 4 KB
    __shared__ unsigned lbase[NBINS];   // 4 KB

    unsigned* cnt  = (unsigned*)(ws + CNT_OFF);
    unsigned* ocnt = (unsigned*)(ws + OCNT_OFF);
    uint2*    ovf  = (uint2*)(ws + OVF_OFF);
    unsigned* rec  = (unsigned*)(ws + REC_OFF);

    const int tid = threadIdx.x;
    const unsigned j0 = blockIdx.x * CHUNK;
    const unsigned j1 = j0 + CHUNK;

    for (int b = tid; b < NBINS; b += BIN_THREADS) lcnt[b] = 0u;
    __syncthreads();

    // pass A: local histogram (coalesced tgt reads)
    for (unsigned j = j0 + tid; j < j1; j += BIN_THREADS)
        atomicAdd(&lcnt[((unsigned)tgt[j]) >> 8], 1u);
    __syncthreads();

    // reserve contiguous ranges: <=1024 global atomics per block
    for (int b = tid; b < NBINS; b += BIN_THREADS) {
        unsigned c = lcnt[b];
        lbase[b] = c ? atomicAdd(&cnt[b], c) : 0u;
        lcnt[b] = 0u;
    }
    __syncthreads();

    // pass B: scatter records into reserved ranges
    for (unsigned j = j0 + tid; j < j1; j += BIN_THREADS) {
        unsigned t = (unsigned)tgt[j];
        unsigned s = (unsigned)src[j];
        unsigned k = j >> 16;                       // P == 65536
        unsigned bin = t >> 8;
        unsigned pos = lbase[bin] + atomicAdd(&lcnt[bin], 1u);
        if (pos < CAP)
            rec[(size_t)bin * CAP + pos] = ((t & 255u) << 23) | (k << 18) | s;
        else {
            unsigned op = atomicAdd(ocnt, 1u);
            if (op < OVF_CAP) ovf[op] = make_uint2((k << 18) | s, t);
        }
    }
}

// ---------- phase 2: per-bin k-run MFMA + LDS accumulation ----------
__global__ __launch_bounds__(512) void conv_bin(
    const float* __restrict__ feat,
    const unsigned char* __restrict__ ws,
    float* __restrict__ out)
{
    __shared__ float tile[(BIN_ROWS + 1) * C];      // row 256 = garbage row
    __shared__ unsigned srec[REC_SLOTS];
    __shared__ unsigned khist[K_VOL], koff[K_VOL];
    __shared__ unsigned short grp2k[MAXG + 2];
    __shared__ unsigned sG;

    const int bin  = blockIdx.x;
    const int tid  = threadIdx.x;
    const int wave = tid >> 6, lane = tid & 63;
    const int g4 = lane >> 4, col = lane & 15;

    const unsigned* cnt = (const unsigned*)(ws + CNT_OFF);
    const unsigned* rec = (const unsigned*)(ws + REC_OFF) + (size_t)bin * CAP;
    const unsigned nrec = min(cnt[bin], (unsigned)CAP);

    for (int i = tid; i < (BIN_ROWS + 1) * C; i += 512) tile[i] = 0.f;
    for (int i = tid; i < REC_SLOTS; i += 512) srec[i] = 0xFFFFFFFFu;
    if (tid < K_VOL) khist[tid] = 0u;
    __syncthreads();

    // k histogram
    for (unsigned i = tid; i < nrec; i += 512)
        atomicAdd(&khist[(rec[i] >> 18) & 31u], 1u);
    __syncthreads();

    // padded segment scan + group->k map (serial, tiny)
    if (tid == 0) {
        unsigned base = 0, g = 0;
        for (int k = 0; k < K_VOL; ++k) {
            koff[k] = base;
            unsigned ng = (khist[k] + 15u) >> 4;
            for (unsigned q = 0; q < ng; ++q) grp2k[g++] = (unsigned short)k;
            base += ng << 4;
        }
        sG = g;
    }
    __syncthreads();
    const unsigned G = sG;

    // scatter records into k-sorted padded LDS slots
    for (unsigned i = tid; i < nrec; i += 512) {
        unsigned r = rec[i];
        unsigned pos = atomicAdd(&koff[(r >> 18) & 31u], 1u);
        srec[pos] = r;
    }
    __syncthreads();

    const bf16x8* whi = (const bf16x8*)(ws + W_HI_OFF);
    const bf16x8* wlo = (const bf16x8*)(ws + W_LO_OFF);
    const unsigned gs = (G * (unsigned)wave) >> 3;
    const unsigned ge = (G * (unsigned)(wave + 1)) >> 3;

    bf16x8 Bhi[2][4], Blo[2][4];

    // distance-1 prefetch state (records + feat row chunk)
    unsigned nmy = 0, nq0 = 0, nq1 = 0, nq2 = 0, nq3 = 0;
    f32x4 ra0{}, ra1{}, ra2{}, ra3{};
    if (gs < ge) {
        const unsigned rb = gs * 16;
        nmy = srec[rb + col];
        nq0 = srec[rb + g4 * 4 + 0];
        nq1 = srec[rb + g4 * 4 + 1];
        nq2 = srec[rb + g4 * 4 + 2];
        nq3 = srec[rb + g4 * 4 + 3];
        const float* fr = feat + (size_t)(nmy & 0x3FFFFu) * C + g4 * 8;
        ra0 = *(const f32x4*)(fr);
        ra1 = *(const f32x4*)(fr + 4);
        ra2 = *(const f32x4*)(fr + 32);
        ra3 = *(const f32x4*)(fr + 36);
    }

    unsigned g = gs;
    while (g < ge) {
        const int k = (int)grp2k[g];
        unsigned gke = g + 1;
        while (gke < ge && (int)grp2k[gke] == k) ++gke;

        // B frags for this k-run (hoisted out of inner loop)
        #pragma unroll
        for (int kt = 0; kt < 2; ++kt)
            #pragma unroll
            for (int nt = 0; nt < 4; ++nt) {
                int idx = ((k * 2 + kt) * 4 + nt) * 64 + lane;
                Bhi[kt][nt] = whi[idx];
                Blo[kt][nt] = wlo[idx];
            }

        for (; g < gke; ++g) {
            const unsigned q0 = nq0, q1 = nq1, q2 = nq2, q3 = nq3;

            // convert prefetched feat -> A frags (ra* dead after)
            bf16x8 Ahi[2], Alo[2];
            #pragma unroll
            for (int i = 0; i < 4; ++i) {
                float x0 = ra0[i], x1 = ra1[i], x2 = ra2[i], x3 = ra3[i];
                unsigned short h;
                h = cvt_bf16_rne(x0); Ahi[0][i]     = (short)h; Alo[0][i]     = (short)cvt_bf16_rne(x0 - bf16f(h));
                h = cvt_bf16_rne(x1); Ahi[0][4 + i] = (short)h; Alo[0][4 + i] = (short)cvt_bf16_rne(x1 - bf16f(h));
                h = cvt_bf16_rne(x2); Ahi[1][i]     = (short)h; Alo[1][i]     = (short)cvt_bf16_rne(x2 - bf16f(h));
                h = cvt_bf16_rne(x3); Ahi[1][4 + i] = (short)h; Alo[1][4 + i] = (short)cvt_bf16_rne(x3 - bf16f(h));
            }

            // prefetch next group's records + feat (independent of MFMAs below)
            if (g + 1 < ge) {
                const unsigned rb = (g + 1) * 16;
                nmy = srec[rb + col];
                nq0 = srec[rb + g4 * 4 + 0];
                nq1 = srec[rb + g4 * 4 + 1];
                nq2 = srec[rb + g4 * 4 + 2];
                nq3 = srec[rb + g4 * 4 + 3];
                const float* fr = feat + (size_t)(nmy & 0x3FFFFu) * C + g4 * 8;
                ra0 = *(const f32x4*)(fr);
                ra1 = *(const f32x4*)(fr + 4);
                ra2 = *(const f32x4*)(fr + 32);
                ra3 = *(const f32x4*)(fr + 36);
            }

            // 24 MFMAs: 4 n-tiles x 2 k-tiles x {hi*hi, lo*hi, hi*lo}
            f32x4 acc[4] = {f32x4{0.f,0.f,0.f,0.f}, f32x4{0.f,0.f,0.f,0.f},
                            f32x4{0.f,0.f,0.f,0.f}, f32x4{0.f,0.f,0.f,0.f}};
            #pragma unroll
            for (int kt = 0; kt < 2; ++kt) {
                #pragma unroll
                for (int nt = 0; nt < 4; ++nt)
                    acc[nt] = __builtin_amdgcn_mfma_f32_16x16x32_bf16(Ahi[kt], Bhi[kt][nt], acc[nt], 0, 0, 0);
                #pragma unroll
                for (int nt = 0; nt < 4; ++nt)
                    acc[nt] = __builtin_amdgcn_mfma_f32_16x16x32_bf16(Alo[kt], Bhi[kt][nt], acc[nt], 0, 0, 0);
                #pragma unroll
                for (int nt = 0; nt < 4; ++nt)
                    acc[nt] = __builtin_amdgcn_mfma_f32_16x16x32_bf16(Ahi[kt], Blo[kt][nt], acc[nt], 0, 0, 0);
            }

            // LDS accumulate; C/D layout row=g4*4+r, col=nt*16+col
            const int row0 = (q0 == 0xFFFFFFFFu) ? 256 : (int)((q0 >> 23) & 255u);
            const int row1 = (q1 == 0xFFFFFFFFu) ? 256 : (int)((q1 >> 23) & 255u);
            const int row2 = (q2 == 0xFFFFFFFFu) ? 256 : (int)((q2 >> 23) & 255u);
            const int row3 = (q3 == 0xFFFFFFFFu) ? 256 : (int)((q3 >> 23) & 255u);
            float* t0 = &tile[row0 * C + col];
            float* t1 = &tile[row1 * C + col];
            float* t2 = &tile[row2 * C + col];
            float* t3 = &tile[row3 * C + col];
            #pragma unroll
            for (int nt = 0; nt < 4; ++nt) {
                atomicAdd(t0 + nt * 16, acc[nt][0]);
                atomicAdd(t1 + nt * 16, acc[nt][1]);
                atomicAdd(t2 + nt * 16, acc[nt][2]);
                atomicAdd(t3 + nt * 16, acc[nt][3]);
            }
        }
    }
    __syncthreads();

    // stream tile out, coalesced, each element written once
    float* ob = out + (size_t)bin * BIN_ROWS * C;
    for (int i = tid * 4; i < BIN_ROWS * C; i += 512 * 4)
        *(float4*)(ob + i) = *(const float4*)&tile[i];
}

// ---------- phase 3: exact-fp32 fixup for overflow records (normally none) ----------
__global__ void ovf_fix(const float* __restrict__ feat, const float* __restrict__ kern,
                        const unsigned char* __restrict__ ws, float* __restrict__ out) {
    const unsigned* ocnt = (const unsigned*)(ws + OCNT_OFF);
    const uint2*    ovf  = (const uint2*)(ws + OVF_OFF);
    const unsigned n = min(*ocnt, (unsigned)OVF_CAP);
    const int ch = threadIdx.x & 63;
    const unsigned r0 = (blockIdx.x * blockDim.x + threadIdx.x) >> 6;
    const unsigned stride = (gridDim.x * blockDim.x) >> 6;
    for (unsigned r = r0; r < n; r += stride) {
        uint2 e = ovf[r];
        unsigned s = e.x & 0x3FFFFu, k = (e.x >> 18) & 31u, t = e.y;
        const float* fr = feat + (size_t)s * C;
        const float* Wk = kern + (size_t)k * C * C + ch;
        float a = 0.f;
        for (int i = 0; i < C; ++i) a = fmaf(fr[i], Wk[(size_t)i * C], a);
        unsafeAtomicAdd(out + (size_t)t * C + ch, a);
    }
}

// ---------- fallback (round-3 kernel) if ws is too small ----------
#define FB_PAIRS_PER_WAVE 256
#define FB_NBATCH 16
__global__ __launch_bounds__(256) void conv_mfma(
    const float* __restrict__ feat, const float* __restrict__ kern,
    const int* __restrict__ src_ids, const int* __restrict__ tgt_ids,
    float* __restrict__ out)
{
    const int k = blockIdx.y, wave = threadIdx.x >> 6, lane = threadIdx.x & 63;
    const int g = lane >> 4, col = lane & 15;
    bf16x8 Bhi[2][4], Blo[2][4];
    {
        const float* Wk = kern + (size_t)k * C * C;
        #pragma unroll
        for (int kt = 0; kt < 2; ++kt)
            #pragma unroll
            for (int nt = 0; nt < 4; ++nt)
                #pragma unroll
                for (int i = 0; i < 8; ++i) {
                    float w = Wk[(size_t)(kt * 32 + g * 8 + i) * C + nt * 16 + col];
                    unsigned short h = cvt_bf16_rne(w);
                    Bhi[kt][nt][i] = (short)h;
                    Blo[kt][nt][i] = (short)cvt_bf16_rne(w - bf16f(h));
                }
    }
    const int pb0 = (blockIdx.x * 4 + wave) * FB_PAIRS_PER_WAVE;
    const int* srcp = src_ids + (size_t)k * P + pb0;
    const int* tgtp = tgt_ids + (size_t)k * P + pb0;
    for (int b = 0; b < FB_NBATCH; ++b) {
        int sv = srcp[b * 16 + col];
        const float* fr = feat + (size_t)sv * C + g * 8;
        f32x4 ra0 = *(const f32x4*)(fr), ra1 = *(const f32x4*)(fr + 4);
        f32x4 ra2 = *(const f32x4*)(fr + 32), ra3 = *(const f32x4*)(fr + 36);
        int tg0 = tgtp[b * 16 + g * 4 + 0], tg1 = tgtp[b * 16 + g * 4 + 1];
        int tg2 = tgtp[b * 16 + g * 4 + 2], tg3 = tgtp[b * 16 + g * 4 + 3];
        bf16x8 Ahi[2], Alo[2];
        #pragma unroll
        for (int i = 0; i < 4; ++i) {
            float x0 = ra0[i], x1 = ra1[i], x2 = ra2[i], x3 = ra3[i];
            unsigned short h;
            h = cvt_bf16_rne(x0); Ahi[0][i]     = (short)h; Alo[0][i]     = (short)cvt_bf16_rne(x0 - bf16f(h));
            h = cvt_bf16_rne(x1); Ahi[0][4 + i] = (short)h; Alo[0][4 + i] = (short)cvt_bf16_rne(x1 - bf16f(h));
            h = cvt_bf16_rne(x2); Ahi[1][i]     = (short)h; Alo[1][i]     = (short)cvt_bf16_rne(x2 - bf16f(h));
            h = cvt_bf16_rne(x3); Ahi[1][4 + i] = (short)h; Alo[1][4 + i] = (short)cvt_bf16_rne(x3 - bf16f(h));
        }
        f32x4 acc[4] = {f32x4{0.f,0.f,0.f,0.f}, f32x4{0.f,0.f,0.f,0.f},
                        f32x4{0.f,0.f,0.f,0.f}, f32x4{0.f,0.f,0.f,0.f}};
        #pragma unroll
        for (int kt = 0; kt < 2; ++kt) {
            #pragma unroll
            for (int nt = 0; nt < 4; ++nt)
                acc[nt] = __builtin_amdgcn_mfma_f32_16x16x32_bf16(Ahi[kt], Bhi[kt][nt], acc[nt], 0, 0, 0);
            #pragma unroll
            for (int nt = 0; nt < 4; ++nt)
                acc[nt] = __builtin_amdgcn_mfma_f32_16x16x32_bf16(Alo[kt], Bhi[kt][nt], acc[nt], 0, 0, 0);
            #pragma unroll
            for (int nt = 0; nt < 4; ++nt)
                acc[nt] = __builtin_amdgcn_mfma_f32_16x16x32_bf16(Ahi[kt], Blo[kt][nt], acc[nt], 0, 0, 0);
        }
        float* o0 = out + (size_t)tg0 * C + col;
        float* o1 = out + (size_t)tg1 * C + col;
        float* o2 = out + (size_t)tg2 * C + col;
        float* o3 = out + (size_t)tg3 * C + col;
        #pragma unroll
        for (int nt = 0; nt < 4; ++nt) {
            unsafeAtomicAdd(o0 + nt * 16, acc[nt][0]);
            unsafeAtomicAdd(o1 + nt * 16, acc[nt][1]);
            unsafeAtomicAdd(o2 + nt * 16, acc[nt][2]);
            unsafeAtomicAdd(o3 + nt * 16, acc[nt][3]);
        }
    }
}

extern "C" void kernel_launch(void* const* d_in, const int* in_sizes, int n_in,
                              void* d_out, int out_size, void* d_ws, size_t ws_size,
                              hipStream_t stream)
{
    const float* feat = (const float*)d_in[0];
    const float* kern = (const float*)d_in[1];
    const int*   src  = (const int*)d_in[2];
    const int*   tgt  = (const int*)d_in[3];
    float* out = (float*)d_out;
    unsigned char* ws = (unsigned char*)d_ws;

    if (ws_size >= WS_NEED) {
        hipMemsetAsync(ws + CNT_OFF, 0, NBINS * 4 + 64, stream);
        w_prep<<<K_VOL, 64, 0, stream>>>(kern, ws);
        binning<<<BIN_BLOCKS, BIN_THREADS, 0, stream>>>(src, tgt, ws);
        conv_bin<<<NBINS, 512, 0, stream>>>(feat, ws, out);
        ovf_fix<<<16, 256, 0, stream>>>(feat, kern, ws, out);
    } else {
        hipMemsetAsync(out, 0, (size_t)N_VOX * C * sizeof(float), stream);
        dim3 grid(P / (FB_PAIRS_PER_WAVE * 4), K_VOL);
        conv_mfma<<<grid, 256, 0, stream>>>(feat, kern, src, tgt, out);
    }
}

// Round 8
// 809.684 us; speedup vs baseline: 1.3924x; 1.0286x over previous
//
#include <hip/hip_runtime.h>

#define N_VOX 262144
#define C 64
#define K_VOL 27
#define P 65536
#define NPAIR (K_VOL * P)

// ---- binning geometry ----
#define BIN_ROWS 256
#define NBINS (N_VOX / BIN_ROWS)       // 1024
#define CAP 2048                       // mean 1728, +7.7 sigma headroom
#define REC_SLOTS 2464                 // CAP + 27*15 k-padding headroom
#define MAXG (REC_SLOTS / 16)          // 154

// ---- ws layout (bytes) ----
#define W_SZ      (K_VOL * 2 * 4 * 64 * 16)        // 221184 per half
#define W_HI_OFF  0
#define W_LO_OFF  W_SZ
#define CNT_OFF   (2 * W_SZ)
#define OCNT_OFF  (CNT_OFF + NBINS * 4)
#define OVF_CAP   4096
#define OVF_OFF   (OCNT_OFF + 64)
#define REC_OFF   (OVF_OFF + OVF_CAP * 8)
#define WS_NEED   ((size_t)REC_OFF + (size_t)NBINS * CAP * 4)   // ~8.87 MB

typedef __attribute__((ext_vector_type(8))) short bf16x8;
typedef __attribute__((ext_vector_type(4))) float f32x4;

__device__ inline unsigned short cvt_bf16_rne(float x) {
    unsigned u = __builtin_bit_cast(unsigned, x);
    u += 0x7fff + ((u >> 16) & 1);
    return (unsigned short)(u >> 16);
}
__device__ inline float bf16f(unsigned short h) {
    unsigned u = (unsigned)h << 16;
    return __builtin_bit_cast(float, u);
}

// ---------- phase 0: W -> bf16 hi/lo MFMA fragments in ws ----------
__global__ void w_prep(const float* __restrict__ kern, unsigned char* __restrict__ ws) {
    const int k = blockIdx.x, lane = threadIdx.x;     // 64 threads
    const int g4 = lane >> 4, col = lane & 15;
    const float* Wk = kern + (size_t)k * C * C;
    bf16x8* hi = (bf16x8*)(ws + W_HI_OFF);
    bf16x8* lo = (bf16x8*)(ws + W_LO_OFF);
    #pragma unroll
    for (int kt = 0; kt < 2; ++kt)
        #pragma unroll
        for (int nt = 0; nt < 4; ++nt) {
            bf16x8 h, l;
            #pragma unroll
            for (int i = 0; i < 8; ++i) {
                float w = Wk[(size_t)(kt * 32 + g4 * 8 + i) * C + nt * 16 + col];
                unsigned short hs = cvt_bf16_rne(w);
                h[i] = (short)hs;
                l[i] = (short)cvt_bf16_rne(w - bf16f(hs));
            }
            int idx = ((k * 2 + kt) * 4 + nt) * 64 + lane;
            hi[idx] = h;
            lo[idx] = l;
        }
}

// ---------- phase 1: two-level binning (LDS histogram + range reservation) ----------
#define BIN_BLOCKS 256
#define BIN_THREADS 512
#define CHUNK (NPAIR / BIN_BLOCKS)     // 6912, exact

__global__ __launch_bounds__(BIN_THREADS) void binning(
    const int* __restrict__ src, const int* __restrict__ tgt,
    unsigned char* __restrict__ ws)
{
    __shared__ unsigned lcnt[NBINS];    // 4 KB
    __shared__ unsigned lbase[NBINS];   // 4 KB

    unsigned* cnt  = (unsigned*)(ws + CNT_OFF);
    unsigned* ocnt = (unsigned*)(ws + OCNT_OFF);
    uint2*    ovf  = (uint2*)(ws + OVF_OFF);
    unsigned* rec  = (unsigned*)(ws + REC_OFF);

    const int tid = threadIdx.x;
    const unsigned j0 = blockIdx.x * CHUNK;
    const unsigned j1 = j0 + CHUNK;

    for (int b = tid; b < NBINS; b += BIN_THREADS) lcnt[b] = 0u;
    __syncthreads();

    // pass A: local histogram (coalesced tgt reads)
    for (unsigned j = j0 + tid; j < j1; j += BIN_THREADS)
        atomicAdd(&lcnt[((unsigned)tgt[j]) >> 8], 1u);
    __syncthreads();

    // reserve contiguous ranges: <=1024 global atomics per block
    for (int b = tid; b < NBINS; b += BIN_THREADS) {
        unsigned c = lcnt[b];
        lbase[b] = c ? atomicAdd(&cnt[b], c) : 0u;
        lcnt[b] = 0u;
    }
    __syncthreads();

    // pass B: scatter records into reserved ranges
    for (unsigned j = j0 + tid; j < j1; j += BIN_THREADS) {
        unsigned t = (unsigned)tgt[j];
        unsigned s = (unsigned)src[j];
        unsigned k = j >> 16;                       // P == 65536
        unsigned bin = t >> 8;
        unsigned pos = lbase[bin] + atomicAdd(&lcnt[bin], 1u);
        if (pos < CAP)
            rec[(size_t)bin * CAP + pos] = ((t & 255u) << 23) | (k << 18) | s;
        else {
            unsigned op = atomicAdd(ocnt, 1u);
            if (op < OVF_CAP) ovf[op] = make_uint2((k << 18) | s, t);
        }
    }
}

// ---------- phase 2: per-bin MFMA, wave-split by output-channel quarter ----------
// Wave w: n-quarter nq = w&3 (B frags = 16 VGPRs only), group parity h = w>>2.
// Kills the round-5/7 pathology: per-wave live set ~70 VGPRs, nothing to spill.
__global__ __launch_bounds__(512) void conv_bin(
    const float* __restrict__ feat,
    const unsigned char* __restrict__ ws,
    float* __restrict__ out)
{
    __shared__ float tile[(BIN_ROWS + 1) * C];      // row 256 = garbage row
    __shared__ unsigned srec[REC_SLOTS];
    __shared__ unsigned khist[K_VOL], koff[K_VOL];
    __shared__ unsigned short grp2k[MAXG + 2];
    __shared__ unsigned sG;

    const int bin  = blockIdx.x;
    const int tid  = threadIdx.x;
    const int wave = tid >> 6, lane = tid & 63;
    const int g4 = lane >> 4, col = lane & 15;
    const int nq = wave & 3;       // output-channel quarter: cols nq*16 .. nq*16+15
    const int h  = wave >> 2;      // group-parity split

    const unsigned* cnt = (const unsigned*)(ws + CNT_OFF);
    const unsigned* rec = (const unsigned*)(ws + REC_OFF) + (size_t)bin * CAP;
    const unsigned nrec = min(cnt[bin], (unsigned)CAP);

    for (int i = tid; i < (BIN_ROWS + 1) * C; i += 512) tile[i] = 0.f;
    for (int i = tid; i < REC_SLOTS; i += 512) srec[i] = 0xFFFFFFFFu;
    if (tid < K_VOL) khist[tid] = 0u;
    __syncthreads();

    // k histogram
    for (unsigned i = tid; i < nrec; i += 512)
        atomicAdd(&khist[(rec[i] >> 18) & 31u], 1u);
    __syncthreads();

    // padded segment scan + group->k map (serial, tiny)
    if (tid == 0) {
        unsigned base = 0, g = 0;
        for (int k = 0; k < K_VOL; ++k) {
            koff[k] = base;
            unsigned ng = (khist[k] + 15u) >> 4;
            for (unsigned q = 0; q < ng; ++q) grp2k[g++] = (unsigned short)k;
            base += ng << 4;
        }
        sG = g;
    }
    __syncthreads();
    const unsigned G = sG;

    // scatter records into k-sorted padded LDS slots
    for (unsigned i = tid; i < nrec; i += 512) {
        unsigned r = rec[i];
        unsigned pos = atomicAdd(&koff[(r >> 18) & 31u], 1u);
        srec[pos] = r;
    }
    __syncthreads();

    const bf16x8* whi = (const bf16x8*)(ws + W_HI_OFF);
    const bf16x8* wlo = (const bf16x8*)(ws + W_LO_OFF);

    bf16x8 Bhi[2], Blo[2];         // this wave's nq slice only: 16 VGPRs
    int curk = -1;

    // distance-1 prefetch state (records + feat row chunk), stride 2 in groups
    unsigned nq0 = 0, nq1 = 0, nq2 = 0, nq3 = 0;
    f32x4 ra0{}, ra1{}, ra2{}, ra3{};
    if ((unsigned)h < G) {
        const unsigned rb = (unsigned)h * 16;
        unsigned nmy = srec[rb + col];
        nq0 = srec[rb + g4 * 4 + 0];
        nq1 = srec[rb + g4 * 4 + 1];
        nq2 = srec[rb + g4 * 4 + 2];
        nq3 = srec[rb + g4 * 4 + 3];
        const float* fr = feat + (size_t)(nmy & 0x3FFFFu) * C + g4 * 8;
        ra0 = *(const f32x4*)(fr);
        ra1 = *(const f32x4*)(fr + 4);
        ra2 = *(const f32x4*)(fr + 32);
        ra3 = *(const f32x4*)(fr + 36);
    }

    for (unsigned g = (unsigned)h; g < G; g += 2) {
        const unsigned q0 = nq0, q1 = nq1, q2 = nq2, q3 = nq3;

        // convert prefetched feat -> A frags (ra* dead after)
        bf16x8 Ahi[2], Alo[2];
        #pragma unroll
        for (int i = 0; i < 4; ++i) {
            float x0 = ra0[i], x1 = ra1[i], x2 = ra2[i], x3 = ra3[i];
            unsigned short hh;
            hh = cvt_bf16_rne(x0); Ahi[0][i]     = (short)hh; Alo[0][i]     = (short)cvt_bf16_rne(x0 - bf16f(hh));
            hh = cvt_bf16_rne(x1); Ahi[0][4 + i] = (short)hh; Alo[0][4 + i] = (short)cvt_bf16_rne(x1 - bf16f(hh));
            hh = cvt_bf16_rne(x2); Ahi[1][i]     = (short)hh; Alo[1][i]     = (short)cvt_bf16_rne(x2 - bf16f(hh));
            hh = cvt_bf16_rne(x3); Ahi[1][4 + i] = (short)hh; Alo[1][4 + i] = (short)cvt_bf16_rne(x3 - bf16f(hh));
        }

        // prefetch next group (g+2): records + feat (independent of MFMAs below)
        if (g + 2 < G) {
            const unsigned rb = (g + 2) * 16;
            unsigned nmy = srec[rb + col];
            nq0 = srec[rb + g4 * 4 + 0];
            nq1 = srec[rb + g4 * 4 + 1];
            nq2 = srec[rb + g4 * 4 + 2];
            nq3 = srec[rb + g4 * 4 + 3];
            const float* fr = feat + (size_t)(nmy & 0x3FFFFu) * C + g4 * 8;
            ra0 = *(const f32x4*)(fr);
            ra1 = *(const f32x4*)(fr + 4);
            ra2 = *(const f32x4*)(fr + 32);
            ra3 = *(const f32x4*)(fr + 36);
        }

        // B slice for this group's k (4 loads, only when k changes)
        const int k = (int)grp2k[g];
        if (k != curk) {
            curk = k;
            #pragma unroll
            for (int kt = 0; kt < 2; ++kt) {
                int idx = ((k * 2 + kt) * 4 + nq) * 64 + lane;
                Bhi[kt] = whi[idx];
                Blo[kt] = wlo[idx];
            }
        }

        // 6 MFMAs: 2 k-tiles x {hi*hi, lo*hi, hi*lo} for this n-quarter
        f32x4 acc = f32x4{0.f, 0.f, 0.f, 0.f};
        #pragma unroll
        for (int kt = 0; kt < 2; ++kt) {
            acc = __builtin_amdgcn_mfma_f32_16x16x32_bf16(Ahi[kt], Bhi[kt], acc, 0, 0, 0);
            acc = __builtin_amdgcn_mfma_f32_16x16x32_bf16(Alo[kt], Bhi[kt], acc, 0, 0, 0);
            acc = __builtin_amdgcn_mfma_f32_16x16x32_bf16(Ahi[kt], Blo[kt], acc, 0, 0, 0);
        }

        // LDS accumulate; C/D layout row=g4*4+r, col=nq*16+col
        const int row0 = (q0 == 0xFFFFFFFFu) ? 256 : (int)((q0 >> 23) & 255u);
        const int row1 = (q1 == 0xFFFFFFFFu) ? 256 : (int)((q1 >> 23) & 255u);
        const int row2 = (q2 == 0xFFFFFFFFu) ? 256 : (int)((q2 >> 23) & 255u);
        const int row3 = (q3 == 0xFFFFFFFFu) ? 256 : (int)((q3 >> 23) & 255u);
        const int cc = nq * 16 + col;
        atomicAdd(&tile[row0 * C + cc], acc[0]);
        atomicAdd(&tile[row1 * C + cc], acc[1]);
        atomicAdd(&tile[row2 * C + cc], acc[2]);
        atomicAdd(&tile[row3 * C + cc], acc[3]);
    }
    __syncthreads();

    // stream tile out, coalesced, each element written once
    float* ob = out + (size_t)bin * BIN_ROWS * C;
    for (int i = tid * 4; i < BIN_ROWS * C; i += 512 * 4)
        *(float4*)(ob + i) = *(const float4*)&tile[i];
}

// ---------- phase 3: exact-fp32 fixup for overflow records (normally none) ----------
__global__ void ovf_fix(const float* __restrict__ feat, const float* __restrict__ kern,
                        const unsigned char* __restrict__ ws, float* __restrict__ out) {
    const unsigned* ocnt = (const unsigned*)(ws + OCNT_OFF);
    const uint2*    ovf  = (const uint2*)(ws + OVF_OFF);
    const unsigned n = min(*ocnt, (unsigned)OVF_CAP);
    const int ch = threadIdx.x & 63;
    const unsigned r0 = (blockIdx.x * blockDim.x + threadIdx.x) >> 6;
    const unsigned stride = (gridDim.x * blockDim.x) >> 6;
    for (unsigned r = r0; r < n; r += stride) {
        uint2 e = ovf[r];
        unsigned s = e.x & 0x3FFFFu, k = (e.x >> 18) & 31u, t = e.y;
        const float* fr = feat + (size_t)s * C;
        const float* Wk = kern + (size_t)k * C * C + ch;
        float a = 0.f;
        for (int i = 0; i < C; ++i) a = fmaf(fr[i], Wk[(size_t)i * C], a);
        unsafeAtomicAdd(out + (size_t)t * C + ch, a);
    }
}

// ---------- fallback (round-3 kernel) if ws is too small ----------
#define FB_PAIRS_PER_WAVE 256
#define FB_NBATCH 16
__global__ __launch_bounds__(256) void conv_mfma(
    const float* __restrict__ feat, const float* __restrict__ kern,
    const int* __restrict__ src_ids, const int* __restrict__ tgt_ids,
    float* __restrict__ out)
{
    const int k = blockIdx.y, wave = threadIdx.x >> 6, lane = threadIdx.x & 63;
    const int g = lane >> 4, col = lane & 15;
    bf16x8 Bhi[2][4], Blo[2][4];
    {
        const float* Wk = kern + (size_t)k * C * C;
        #pragma unroll
        for (int kt = 0; kt < 2; ++kt)
            #pragma unroll
            for (int nt = 0; nt < 4; ++nt)
                #pragma unroll
                for (int i = 0; i < 8; ++i) {
                    float w = Wk[(size_t)(kt * 32 + g * 8 + i) * C + nt * 16 + col];
                    unsigned short h = cvt_bf16_rne(w);
                    Bhi[kt][nt][i] = (short)h;
                    Blo[kt][nt][i] = (short)cvt_bf16_rne(w - bf16f(h));
                }
    }
    const int pb0 = (blockIdx.x * 4 + wave) * FB_PAIRS_PER_WAVE;
    const int* srcp = src_ids + (size_t)k * P + pb0;
    const int* tgtp = tgt_ids + (size_t)k * P + pb0;
    for (int b = 0; b < FB_NBATCH; ++b) {
        int sv = srcp[b * 16 + col];
        const float* fr = feat + (size_t)sv * C + g * 8;
        f32x4 ra0 = *(const f32x4*)(fr), ra1 = *(const f32x4*)(fr + 4);
        f32x4 ra2 = *(const f32x4*)(fr + 32), ra3 = *(const f32x4*)(fr + 36);
        int tg0 = tgtp[b * 16 + g * 4 + 0], tg1 = tgtp[b * 16 + g * 4 + 1];
        int tg2 = tgtp[b * 16 + g * 4 + 2], tg3 = tgtp[b * 16 + g * 4 + 3];
        bf16x8 Ahi[2], Alo[2];
        #pragma unroll
        for (int i = 0; i < 4; ++i) {
            float x0 = ra0[i], x1 = ra1[i], x2 = ra2[i], x3 = ra3[i];
            unsigned short h;
            h = cvt_bf16_rne(x0); Ahi[0][i]     = (short)h; Alo[0][i]     = (short)cvt_bf16_rne(x0 - bf16f(h));
            h = cvt_bf16_rne(x1); Ahi[0][4 + i] = (short)h; Alo[0][4 + i] = (short)cvt_bf16_rne(x1 - bf16f(h));
            h = cvt_bf16_rne(x2); Ahi[1][i]     = (short)h; Alo[1][i]     = (short)cvt_bf16_rne(x2 - bf16f(h));
            h = cvt_bf16_rne(x3); Ahi[1][4 + i] = (short)h; Alo[1][4 + i] = (short)cvt_bf16_rne(x3 - bf16f(h));
        }
        f32x4 acc[4] = {f32x4{0.f,0.f,0.f,0.f}, f32x4{0.f,0.f,0.f,0.f},
                        f32x4{0.f,0.f,0.f,0.f}, f32x4{0.f,0.f,0.f,0.f}};
        #pragma unroll
        for (int kt = 0; kt < 2; ++kt) {
            #pragma unroll
            for (int nt = 0; nt < 4; ++nt)
                acc[nt] = __builtin_amdgcn_mfma_f32_16x16x32_bf16(Ahi[kt], Bhi[kt][nt], acc[nt], 0, 0, 0);
            #pragma unroll
            for (int nt = 0; nt < 4; ++nt)
                acc[nt] = __builtin_amdgcn_mfma_f32_16x16x32_bf16(Alo[kt], Bhi[kt][nt], acc[nt], 0, 0, 0);
            #pragma unroll
            for (int nt = 0; nt < 4; ++nt)
                acc[nt] = __builtin_amdgcn_mfma_f32_16x16x32_bf16(Ahi[kt], Blo[kt][nt], acc[nt], 0, 0, 0);
        }
        float* o0 = out + (size_t)tg0 * C + col;
        float* o1 = out + (size_t)tg1 * C + col;
        float* o2 = out + (size_t)tg2 * C + col;
        float* o3 = out + (size_t)tg3 * C + col;
        #pragma unroll
        for (int nt = 0; nt < 4; ++nt) {
            unsafeAtomicAdd(o0 + nt * 16, acc[nt][0]);
            unsafeAtomicAdd(o1 + nt * 16, acc[nt][1]);
            unsafeAtomicAdd(o2 + nt * 16, acc[nt][2]);
            unsafeAtomicAdd(o3 + nt * 16, acc[nt][3]);
        }
    }
}

extern "C" void kernel_launch(void* const* d_in, const int* in_sizes, int n_in,
                              void* d_out, int out_size, void* d_ws, size_t ws_size,
                              hipStream_t stream)
{
    const float* feat = (const float*)d_in[0];
    const float* kern = (const float*)d_in[1];
    const int*   src  = (const int*)d_in[2];
    const int*   tgt  = (const int*)d_in[3];
    float* out = (float*)d_out;
    unsigned char* ws = (unsigned char*)d_ws;

    if (ws_size >= WS_NEED) {
        hipMemsetAsync(ws + CNT_OFF, 0, NBINS * 4 + 64, stream);
        w_prep<<<K_VOL, 64, 0, stream>>>(kern, ws);
        binning<<<BIN_BLOCKS, BIN_THREADS, 0, stream>>>(src, tgt, ws);
        conv_bin<<<NBINS, 512, 0, stream>>>(feat, ws, out);
        ovf_fix<<<16, 256, 0, stream>>>(feat, kern, ws, out);
    } else {
        hipMemsetAsync(out, 0, (size_t)N_VOX * C * sizeof(float), stream);
        dim3 grid(P / (FB_PAIRS_PER_WAVE * 4), K_VOL);
        conv_mfma<<<grid, 256, 0, stream>>>(feat, kern, src, tgt, out);
    }
}